// Round 5
// baseline (66.685 us; speedup 1.0000x reference)
//
#include <hip/hip_runtime.h>
#include <math.h>

// Cox partial-likelihood loss, N fixed at 8192 by the reference.
//
// v6: single-dispatch fusion WITHOUT inter-block sync. History:
//  - v3 (verified, 65.2us): sweep(512x512) -> partials, + reduce dispatch.
//  - v4 (spin on tagged slots) hung: no co-residency guarantee for plain
//    launches -> a non-resident block leaves block 0 spinning forever.
//  - v5 (hipLaunchCooperativeKernel) failed: cooperative launches are not
//    capturable by the harness's hip-graph timing path.
//  Lesson: no inter-block waiting of ANY kind in this harness.
// So the reduce is folded back the v1-proven way: one device atomicAdd per
// block onto out[0]. v1 already demonstrated (passed, absmax 0.0) that
// atomics onto the 0xAA-poisoned out are harmless (+poison ~ -3e-13 per
// float, additive error far below the 8.4e-2 threshold; the correctness
// call sees a zeroed out). With 256 blocks the serialized same-address
// drain is ~half of v1's (~2-3us), and we delete the reduce dispatch and
// its inter-dispatch gap (~3-4us).
// Sweep: 256 blocks x 1024 threads (16 waves), 64KB LDS, 4 waves/SIMD --
// v4's verified indexing. Each wave-pair owns 4 rows; halves of j split
// across the pair; combined through LDS.
constexpr int CN  = 8192;
constexpr int TPB = 1024;         // 16 waves per block
constexpr int IPB = 32;           // i's per block (4 per wave-pair)
constexpr int NB  = CN / IPB;     // 256 blocks

__global__ __launch_bounds__(TPB, 4) void cox_fused(
    const float* __restrict__ hazards,
    const float* __restrict__ time_,
    const int*   __restrict__ c,
    float* __restrict__ out) {
  __shared__ __align__(16) float t_s[CN];
  __shared__ __align__(16) float e_s[CN];
  __shared__ float wred[16][4];

  const int tid = threadIdx.x;

  // Epilogue operands loaded early so their latency hides under the sweep.
  int   ci = 0;
  float hi = 0.f;
  if (tid < IPB) {
    const int i = blockIdx.x * IPB + tid;
    ci = c[i];
    hi = hazards[i];
  }

  // ---- Stage all j's: time + exp(theta). 2 float4-pairs per thread. ----
  {
    const float4* tg = reinterpret_cast<const float4*>(time_);
    const float4* hg = reinterpret_cast<const float4*>(hazards);
    float4* t4s = reinterpret_cast<float4*>(t_s);
    float4* e4s = reinterpret_cast<float4*>(e_s);
    #pragma unroll
    for (int k = tid; k < CN / 4; k += TPB) {
      float4 tv = tg[k];
      float4 hv = hg[k];
      t4s[k] = tv;
      e4s[k] = make_float4(expf(hv.x), expf(hv.y), expf(hv.z), expf(hv.w));
    }
  }
  __syncthreads();

  const int wave = tid >> 6;
  const int lane = tid & 63;
  const int pair = wave >> 1;  // i-group 0..7 (4 rows each)
  const int half = wave & 1;   // which 4096-j half
  const int ibase = blockIdx.x * IPB + pair * 4;

  // Wave-uniform i-times (broadcast loads).
  const float ti0 = time_[ibase + 0];
  const float ti1 = time_[ibase + 1];
  const float ti2 = time_[ibase + 2];
  const float ti3 = time_[ibase + 3];

  // ---- Main sweep over this wave's j-half: lane l reads float4 index
  // jbase + k*64 + l (16 B/lane, consecutive across lanes -> conflict-free
  // ds_read_b128). Each float4 pair feeds 16 compare-selects. ----
  float a0 = 0.f, a1 = 0.f, a2 = 0.f, a3 = 0.f;
  const float4* t4 = reinterpret_cast<const float4*>(t_s);
  const float4* e4 = reinterpret_cast<const float4*>(e_s);
  const int jbase = half * (CN / 8);  // float4 index: 0 or 1024
  #pragma unroll 4
  for (int k = 0; k < 16; ++k) {
    const int idx = jbase + k * 64 + lane;
    float4 t = t4[idx];
    float4 e = e4[idx];
    a0 += (t.x >= ti0) ? e.x : 0.f;
    a0 += (t.y >= ti0) ? e.y : 0.f;
    a0 += (t.z >= ti0) ? e.z : 0.f;
    a0 += (t.w >= ti0) ? e.w : 0.f;
    a1 += (t.x >= ti1) ? e.x : 0.f;
    a1 += (t.y >= ti1) ? e.y : 0.f;
    a1 += (t.z >= ti1) ? e.z : 0.f;
    a1 += (t.w >= ti1) ? e.w : 0.f;
    a2 += (t.x >= ti2) ? e.x : 0.f;
    a2 += (t.y >= ti2) ? e.y : 0.f;
    a2 += (t.z >= ti2) ? e.z : 0.f;
    a2 += (t.w >= ti2) ? e.w : 0.f;
    a3 += (t.x >= ti3) ? e.x : 0.f;
    a3 += (t.y >= ti3) ? e.y : 0.f;
    a3 += (t.z >= ti3) ? e.z : 0.f;
    a3 += (t.w >= ti3) ? e.w : 0.f;
  }

  // ---- Full-wave butterfly: every lane ends with its half's sums. ----
  #pragma unroll
  for (int off = 1; off < 64; off <<= 1) {
    a0 += __shfl_xor(a0, off, 64);
    a1 += __shfl_xor(a1, off, 64);
    a2 += __shfl_xor(a2, off, 64);
    a3 += __shfl_xor(a3, off, 64);
  }

  // ---- Combine the two j-halves of each i-group through LDS. ----
  if (lane < 4) {
    float r = (lane == 0) ? a0 : (lane == 1) ? a1 : (lane == 2) ? a2 : a3;
    wred[wave][lane] = r;
  }
  __syncthreads();

  // ---- Loss contribution for this block's 32 i's (wave 0, lanes 0..31). ----
  float contrib = 0.f;
  if (tid < IPB) {
    const int p = tid >> 2;  // i-group
    const int q = tid & 3;   // row within group
    float r = wred[2 * p][q] + wred[2 * p + 1][q];
    if (ci != 0) contrib = hi - logf(r);
  }
  // Sum lanes 0..31 (all within wave 0).
  contrib += __shfl_xor(contrib, 1, 64);
  contrib += __shfl_xor(contrib, 2, 64);
  contrib += __shfl_xor(contrib, 4, 64);
  contrib += __shfl_xor(contrib, 8, 64);
  contrib += __shfl_xor(contrib, 16, 64);

  // One atomic per block onto out[0] (v1-proven poison semantics).
  if (tid == 0) {
    atomicAdd(out, -contrib / (float)CN);
  }
}

extern "C" void kernel_launch(void* const* d_in, const int* in_sizes, int n_in,
                              void* d_out, int out_size, void* d_ws, size_t ws_size,
                              hipStream_t stream) {
  const float* hazards = (const float*)d_in[0];
  const float* time_   = (const float*)d_in[1];
  const int*   c       = (const int*)d_in[2];
  float* out = (float*)d_out;
  cox_fused<<<NB, TPB, 0, stream>>>(hazards, time_, c, out);
}

// Round 6
// 65.603 us; speedup vs baseline: 1.0165x; 1.0165x over previous
//
#include <hip/hip_runtime.h>
#include <math.h>

// Cox partial-likelihood loss, N fixed at 8192 by the reference.
//
// v7 = v3 (best verified: 65.2us) with a minimal single-wave reduce.
// Evidence ranking of endings (measured):
//   v3 partial-stores + reduce dispatch : 65.2us   <- best
//   v6 fused, 256 same-addr atomics     : 66.7us   (drain > dispatch cost)
//   v2 fused, 512 same-addr atomics     : 67.7us
//   v4 spin-fusion: HANG (no co-residency guarantee for plain launches)
//   v5 cooperative: FAIL (not capturable by the harness's hip-graph timing)
// Sweep is at floor (~3us; halving per-wave work moved only -1.6us) and the
// 39.5us ws-poison fill is unconditional (v6 didn't use d_ws; fill stayed).
// Remaining controllable cost is the reduce dispatch: shrink it to ONE
// 64-lane wave (2 float4 loads/lane, butterfly, store) -- strictly less
// work than v3's 512-thread/8-wave/LDS version.
constexpr int CN  = 8192;
constexpr int TPB = 512;          // 8 waves per block
constexpr int IPB = 16;           // i's per block (4 per wave-quad)
constexpr int NB  = CN / IPB;     // 512 blocks -> 2 blocks/CU, 16 waves/CU

__global__ __launch_bounds__(TPB, 4) void cox_sweep(
    const float* __restrict__ hazards,
    const float* __restrict__ time_,
    const int*   __restrict__ c,
    float* __restrict__ partial) {
  __shared__ __align__(16) float t_s[CN];
  __shared__ __align__(16) float e_s[CN];
  __shared__ float wred[8][4];

  const int tid = threadIdx.x;

  // Epilogue operands loaded EARLY so their global-load latency hides under
  // the sweep.
  int   ci = 0;
  float hi = 0.f;
  if (tid < IPB) {
    const int i = blockIdx.x * IPB + tid;
    ci = c[i];
    hi = hazards[i];
  }

  // ---- Stage all j's: time + exp(theta). 4 float4-pairs per thread. ----
  {
    const float4* tg = reinterpret_cast<const float4*>(time_);
    const float4* hg = reinterpret_cast<const float4*>(hazards);
    float4* t4s = reinterpret_cast<float4*>(t_s);
    float4* e4s = reinterpret_cast<float4*>(e_s);
    #pragma unroll
    for (int k = tid; k < CN / 4; k += TPB) {
      float4 tv = tg[k];
      float4 hv = hg[k];
      t4s[k] = tv;
      e4s[k] = make_float4(expf(hv.x), expf(hv.y), expf(hv.z), expf(hv.w));
    }
  }
  __syncthreads();

  const int wave = tid >> 6;
  const int lane = tid & 63;
  const int quad = wave & 3;   // which group of 4 rows
  const int half = wave >> 2;  // which 4096-j half
  const int ibase = blockIdx.x * IPB + quad * 4;

  // Wave-uniform i-times (broadcast loads).
  const float ti0 = time_[ibase + 0];
  const float ti1 = time_[ibase + 1];
  const float ti2 = time_[ibase + 2];
  const float ti3 = time_[ibase + 3];

  // ---- Main sweep over this wave's j-half: lane l reads float4 index
  // jbase + k*64 + l (16 B/lane, consecutive across lanes -> conflict-free
  // ds_read_b128). Each float4 pair feeds 16 compare-selects. ----
  float a0 = 0.f, a1 = 0.f, a2 = 0.f, a3 = 0.f;
  const float4* t4 = reinterpret_cast<const float4*>(t_s);
  const float4* e4 = reinterpret_cast<const float4*>(e_s);
  const int jbase = half * (CN / 8);  // float4 index: 0 or 1024
  #pragma unroll 4
  for (int k = 0; k < CN / 4 / 64 / 2; ++k) {  // 16 iterations
    const int idx = jbase + k * 64 + lane;
    float4 t = t4[idx];
    float4 e = e4[idx];
    a0 += (t.x >= ti0) ? e.x : 0.f;
    a0 += (t.y >= ti0) ? e.y : 0.f;
    a0 += (t.z >= ti0) ? e.z : 0.f;
    a0 += (t.w >= ti0) ? e.w : 0.f;
    a1 += (t.x >= ti1) ? e.x : 0.f;
    a1 += (t.y >= ti1) ? e.y : 0.f;
    a1 += (t.z >= ti1) ? e.z : 0.f;
    a1 += (t.w >= ti1) ? e.w : 0.f;
    a2 += (t.x >= ti2) ? e.x : 0.f;
    a2 += (t.y >= ti2) ? e.y : 0.f;
    a2 += (t.z >= ti2) ? e.z : 0.f;
    a2 += (t.w >= ti2) ? e.w : 0.f;
    a3 += (t.x >= ti3) ? e.x : 0.f;
    a3 += (t.y >= ti3) ? e.y : 0.f;
    a3 += (t.z >= ti3) ? e.z : 0.f;
    a3 += (t.w >= ti3) ? e.w : 0.f;
  }

  // ---- Full-wave butterfly: every lane ends with its half's sums. ----
  #pragma unroll
  for (int off = 1; off < 64; off <<= 1) {
    a0 += __shfl_xor(a0, off, 64);
    a1 += __shfl_xor(a1, off, 64);
    a2 += __shfl_xor(a2, off, 64);
    a3 += __shfl_xor(a3, off, 64);
  }

  // ---- Combine the two j-halves of each quad through LDS. ----
  if (lane < 4) {
    float r = (lane == 0) ? a0 : (lane == 1) ? a1 : (lane == 2) ? a2 : a3;
    wred[wave][lane] = r;
  }
  __syncthreads();

  // ---- Loss contribution for this block's 16 i's (wave 0, lanes 0..15). ----
  float contrib = 0.f;
  if (tid < 16) {
    const int w0 = tid >> 2;          // quad
    const int q  = tid & 3;           // row within quad
    float r = wred[w0][q] + wred[w0 + 4][q];
    if (ci != 0) contrib = hi - logf(r);
  }
  contrib += __shfl_xor(contrib, 1, 64);
  contrib += __shfl_xor(contrib, 2, 64);
  contrib += __shfl_xor(contrib, 4, 64);
  contrib += __shfl_xor(contrib, 8, 64);

  // Plain store of the block partial -- 512 distinct addresses.
  if (tid == 0) partial[blockIdx.x] = contrib;
}

// Single-wave finisher: 64 lanes x 2 float4 = 512 partials, butterfly,
// direct store to out[0] (no dependence on out pre-zeroing, no LDS, no
// barriers).
__global__ __launch_bounds__(64) void cox_reduce(
    const float* __restrict__ partial,
    float* __restrict__ out) {
  const int lane = threadIdx.x;
  const float4* p4 = reinterpret_cast<const float4*>(partial);
  float4 u = p4[lane];
  float4 v = p4[lane + 64];
  float s = u.x + u.y + u.z + u.w + v.x + v.y + v.z + v.w;
  #pragma unroll
  for (int off = 1; off < 64; off <<= 1) s += __shfl_xor(s, off, 64);
  if (lane == 0) out[0] = -s / (float)CN;
}

extern "C" void kernel_launch(void* const* d_in, const int* in_sizes, int n_in,
                              void* d_out, int out_size, void* d_ws, size_t ws_size,
                              hipStream_t stream) {
  const float* hazards = (const float*)d_in[0];
  const float* time_   = (const float*)d_in[1];
  const int*   c       = (const int*)d_in[2];
  float* partial = (float*)d_ws;   // 512 floats, fully overwritten each call
  float* out = (float*)d_out;
  cox_sweep<<<NB, TPB, 0, stream>>>(hazards, time_, c, partial);
  cox_reduce<<<1, 64, 0, stream>>>(partial, out);
}